// Round 12
// baseline (151.354 us; speedup 1.0000x reference)
//
#include <hip/hip_runtime.h>
#include <hip/hip_bf16.h>
#include <cmath>

// GRU cell fused, round 12: round-11 (32x32x16 MFMA, lane-linear fragments,
// 2-barrier dbuf shell) with the prepass element-order FIX:
//   ksub-tile stored [khalf(2)][row(32)][8k]  (was [row][half][8k] -> scrambled rows)
// so lane-linear read offset lane*8 yields the HW mapping row=lane&31,
// k=(lane>>5)*8+elem for both A and B operands.
// C/D mapping (HW-verified m74/m101): col=lane&31, row=(r&3)+8*(r>>2)+4*(lane>>5)
// ws layout (ushort elems):
//   wsIn  @ 0        : [256 mt][32 kt][2 ksub][2 khalf][32 row][8 k]  8,388,608
//   wsHx  @ 8388608  : same
//   wsWih @ 16777216 : [64 ct][32 kt][2 ksub][2 khalf][32 row][8 k]   2,097,152
//   wsWhh @ 18874368 : same
//   wsWc  @ 20971520 : [32 ct][...]                                   1,048,576
//   wsWhc @ 22020096 : same

typedef __attribute__((ext_vector_type(8)))  short bf16x8;
typedef __attribute__((ext_vector_type(16))) float f32x16;
typedef unsigned int u32;

typedef const __attribute__((address_space(1))) u32 gu32;
typedef __attribute__((address_space(3))) u32 su32;

__device__ __forceinline__ unsigned short f2bf(float f) {
  union { float f; u32 u; } v; v.f = f;
  u32 u = v.u;
  u += 0x7FFFu + ((u >> 16) & 1u);   // RTNE
  return (unsigned short)(u >> 16);
}
__device__ __forceinline__ void gload16(void* ldsp, const void* gp) {
  __builtin_amdgcn_global_load_lds((gu32*)gp, (su32*)ldsp, 16, 0, 0);
}
__device__ __forceinline__ float sigmf(float x) { return 1.0f / (1.0f + __expf(-x)); }

// ---------------- prepass: fp32 -> bf16 lane-linear 32x32 fragment images ----------------
__global__ __launch_bounds__(256) void cvt_all(
    const float* __restrict__ In, const float* __restrict__ Hx,
    const float* __restrict__ Wih, const float* __restrict__ Whh,
    const float* __restrict__ Wc,  const float* __restrict__ Whc,
    unsigned short* __restrict__ wsIn, unsigned short* __restrict__ wsHx,
    unsigned short* __restrict__ wsWih, unsigned short* __restrict__ wsWhh,
    unsigned short* __restrict__ wsWc,  unsigned short* __restrict__ wsWhc)
{
  int bid = blockIdx.x;
  if (bid < 8192) {
    int gid = bid * 256 + threadIdx.x;       // 2 * 2^20 16B-slots
    const float* src; unsigned short* dst; int idx;
    if (gid < (1 << 20)) { src = In; dst = wsIn; idx = gid; }
    else                 { src = Hx; dst = wsHx; idx = gid - (1 << 20); }
    int m = idx >> 7, t = idx & 127;         // k0 = t*8
    const float4* s = (const float4*)(src + (size_t)m * 1024 + t * 8);
    float4 a = s[0], b = s[1];
    int mt = m >> 5, row = m & 31;
    int kt = t >> 2, ksub = (t >> 1) & 1, half = t & 1;
    bf16x8 v;
    v[0] = (short)f2bf(a.x); v[1] = (short)f2bf(a.y); v[2] = (short)f2bf(a.z); v[3] = (short)f2bf(a.w);
    v[4] = (short)f2bf(b.x); v[5] = (short)f2bf(b.y); v[6] = (short)f2bf(b.z); v[7] = (short)f2bf(b.w);
    *(bf16x8*)(dst + ((size_t)(mt * 32 + kt) * 2 + ksub) * 512 + half * 256 + row * 8) = v;
  } else {
    int wb = bid - 8192;
    const float* W; unsigned short* dst; int NW; int local;
    if (wb < 1024)      { W = Wih; dst = wsWih; NW = 2048; local = wb; }
    else if (wb < 2048) { W = Whh; dst = wsWhh; NW = 2048; local = wb - 1024; }
    else if (wb < 2560) { W = Wc;  dst = wsWc;  NW = 1024; local = wb - 2048; }
    else                { W = Whc; dst = wsWhc; NW = 1024; local = wb - 2560; }
    int nb = local >> 5, kb = local & 31;
    int tid = threadIdx.x;
    int n  = nb * 64 + (tid & 63);
    int k0 = kb * 32 + (tid >> 6) * 8;
    bf16x8 v;
    #pragma unroll
    for (int b = 0; b < 8; ++b) v[b] = (short)f2bf(W[(size_t)(k0 + b) * NW + n]);
    int ct = n >> 5, row = n & 31;
    int ksub = (tid >> 7), half = (tid >> 6) & 1;
    *(bf16x8*)(dst + ((size_t)(ct * 32 + kb) * 2 + ksub) * 512 + half * 256 + row * 8) = v;
  }
}

// ---------------- fused GEMM + GRU epilogue, 32x32x16 MFMA ----------------
// block: 256 thr = 4 waves (2m x 2n), tile BM=128 x BN=64, BK=32, dbuf 80KB.
// Per buffer (40 chunks x 1KB): In c0-7 [(mtl)*2+ksub], Hx c8-15,
//   W c16-39: mat*4 + ct_sel*2 + ksub; mat: 0=Wih_z 1=Whh_z 2=Wih_r 3=Whh_r 4=Wc 5=Whc
__global__ __launch_bounds__(256, 2) void gru_gemm(
    const unsigned short* __restrict__ wsIn, const unsigned short* __restrict__ wsHx,
    const unsigned short* __restrict__ wsWih, const unsigned short* __restrict__ wsWhh,
    const unsigned short* __restrict__ wsWc, const unsigned short* __restrict__ wsWhc,
    const float* __restrict__ Hx,
    const float* __restrict__ bih, const float* __restrict__ bhh,
    const float* __restrict__ bc, const float* __restrict__ bhc,
    float* __restrict__ out)
{
  __shared__ unsigned short lds[40960];   // 80 KB = 2 x 40 KB
  const int tid  = threadIdx.x;
  const int lane = tid & 63;
  const int wave = tid >> 6;
  const int wm = wave >> 1, wn = wave & 1;
  const int bid = blockIdx.x;
  const int j = bid & 15;     // n-block (64 cols)
  const int i = bid >> 4;     // m-block (128 rows = 4 mtiles)
  const int lo = lane * 8;    // lane-linear ushort offset within a 1KB chunk

  // per-wave staging plan: 10 chunks of 1KB; uniform stride 1024 ushorts/kt
  const unsigned short* srcB[10];
  #pragma unroll
  for (int c0 = 0; c0 < 10; ++c0) {
    int c = wave * 10 + c0;
    const unsigned short* p;
    if (c < 8) {                 // In: mt = i*4 + (c>>1), ksub = c&1
      p = wsIn + ((size_t)(i * 4 + (c >> 1)) * 64 + (c & 1)) * 512;
    } else if (c < 16) {
      int cc = c - 8;
      p = wsHx + ((size_t)(i * 4 + (cc >> 1)) * 64 + (cc & 1)) * 512;
    } else {
      int cc = c - 16, mat = cc >> 2, q = cc & 3, cs = q >> 1, s = q & 1;
      const unsigned short* base; int ct;
      if (mat == 0)      { base = wsWih; ct = 2 * j + cs; }
      else if (mat == 1) { base = wsWhh; ct = 2 * j + cs; }
      else if (mat == 2) { base = wsWih; ct = 32 + 2 * j + cs; }
      else if (mat == 3) { base = wsWhh; ct = 32 + 2 * j + cs; }
      else if (mat == 4) { base = wsWc;  ct = 2 * j + cs; }
      else               { base = wsWhc; ct = 2 * j + cs; }
      p = base + ((size_t)ct * 64 + s) * 512;
    }
    srcB[c0] = p + lo;
  }
  const int stageOff = (wave * 10) * 512;

  f32x16 accZ[2], accR[2], accC[2], accH[2];
  #pragma unroll
  for (int a = 0; a < 2; ++a) {
    accZ[a] = (f32x16)(0.0f); accR[a] = (f32x16)(0.0f);
    accC[a] = (f32x16)(0.0f); accH[a] = (f32x16)(0.0f);
  }

  auto stage = [&](int bufBase, int kt) {
    #pragma unroll
    for (int c0 = 0; c0 < 10; ++c0)
      gload16((void*)&lds[bufBase + stageOff + c0 * 512],
              (const void*)(srcB[c0] + (size_t)kt * 1024));
  };

  #define MFMA32(a, b, c) __builtin_amdgcn_mfma_f32_32x32x16_bf16(a, b, c, 0, 0, 0)

  auto compute = [&](const unsigned short* __restrict__ L) {
    bf16x8 aIn[2][2], aHx[2][2], w[6][2];
    #pragma unroll
    for (int mtl = 0; mtl < 2; ++mtl)
      #pragma unroll
      for (int s = 0; s < 2; ++s) {
        aIn[mtl][s] = *(const bf16x8*)&L[((wm * 2 + mtl) * 2 + s) * 512 + lo];
        aHx[mtl][s] = *(const bf16x8*)&L[(8 + (wm * 2 + mtl) * 2 + s) * 512 + lo];
      }
    #pragma unroll
    for (int mat = 0; mat < 6; ++mat)
      #pragma unroll
      for (int s = 0; s < 2; ++s)
        w[mat][s] = *(const bf16x8*)&L[(16 + mat * 4 + wn * 2 + s) * 512 + lo];

    #pragma unroll
    for (int s = 0; s < 2; ++s)
      #pragma unroll
      for (int mtl = 0; mtl < 2; ++mtl) {
        accZ[mtl] = MFMA32(aIn[mtl][s], w[0][s], accZ[mtl]);
        accZ[mtl] = MFMA32(aHx[mtl][s], w[1][s], accZ[mtl]);
        accR[mtl] = MFMA32(aIn[mtl][s], w[2][s], accR[mtl]);
        accR[mtl] = MFMA32(aHx[mtl][s], w[3][s], accR[mtl]);
        accC[mtl] = MFMA32(aIn[mtl][s], w[4][s], accC[mtl]);
        accH[mtl] = MFMA32(aHx[mtl][s], w[5][s], accH[mtl]);
      }
  };

  // prologue
  stage(0, 0);
  __syncthreads();

  #pragma unroll 1
  for (int it = 0; it < 16; ++it) {
    const int s = it * 2;
    stage(20480, s + 1);
    compute(&lds[0]);
    __syncthreads();
    if (it < 15) stage(0, s + 2);
    compute(&lds[20480]);
    __syncthreads();
  }

  // ---------- epilogue: C/D col = lane&31 (n), row = (r&3)+8*(r>>2)+4*(lane>>5) ----------
  const int n = j * 64 + wn * 32 + (lane & 31);
  const float bz  = bih[n] + bhh[n];
  const float br  = bih[1024 + n] + bhh[1024 + n];
  const float bcv = bc[n], bhcv = bhc[n];
  const int rowb = 4 * (lane >> 5);
  #pragma unroll
  for (int mtl = 0; mtl < 2; ++mtl) {
    #pragma unroll
    for (int r = 0; r < 16; ++r) {
      int row = (r & 3) + 8 * (r >> 2) + rowb;
      int m = i * 128 + wm * 64 + mtl * 32 + row;
      float z  = sigmf(accZ[mtl][r] + bz);
      float rr = sigmf(accR[mtl][r] + br);
      float cd = tanhf(accC[mtl][r] + bcv + rr * (accH[mtl][r] + bhcv));
      float h  = Hx[(size_t)m * 1024 + n];
      out[(size_t)m * 1024 + n] = (1.0f - z) * h + z * cd;
    }
  }
  #undef MFMA32
}

// ---------------- last-resort fp32 fallback ----------------
__global__ __launch_bounds__(256) void gru_fallback(
    const float* __restrict__ In, const float* __restrict__ Hx,
    const float* __restrict__ Wih, const float* __restrict__ bih,
    const float* __restrict__ Whh, const float* __restrict__ bhh,
    const float* __restrict__ Wc, const float* __restrict__ bc,
    const float* __restrict__ Whc, const float* __restrict__ bhc,
    float* __restrict__ out)
{
  __shared__ float sIn[64][17], sHx[64][17];
  __shared__ float sW[6][16][68];
  const int tid = threadIdx.x;
  const int j = blockIdx.x & 15, i = blockIdx.x >> 4;
  const int tx = tid & 15, ty = tid >> 4;
  float accZ[4][4] = {}, accR[4][4] = {}, accC[4][4] = {}, accH[4][4] = {};
  const int ms = tid >> 2, kq = (tid & 3) * 4;
  const int wk = tid >> 4, wn4 = (tid & 15) * 4;
  for (int k0 = 0; k0 < 1024; k0 += 16) {
    __syncthreads();
    {
      float4 a = *(const float4*)&In[(size_t)(i * 64 + ms) * 1024 + k0 + kq];
      sIn[ms][kq] = a.x; sIn[ms][kq + 1] = a.y; sIn[ms][kq + 2] = a.z; sIn[ms][kq + 3] = a.w;
      float4 b = *(const float4*)&Hx[(size_t)(i * 64 + ms) * 1024 + k0 + kq];
      sHx[ms][kq] = b.x; sHx[ms][kq + 1] = b.y; sHx[ms][kq + 2] = b.z; sHx[ms][kq + 3] = b.w;
    }
    {
      float4 w0 = *(const float4*)&Wih[(size_t)(k0 + wk) * 2048 + j * 64 + wn4];
      float4 w1 = *(const float4*)&Wih[(size_t)(k0 + wk) * 2048 + 1024 + j * 64 + wn4];
      float4 w2 = *(const float4*)&Whh[(size_t)(k0 + wk) * 2048 + j * 64 + wn4];
      float4 w3 = *(const float4*)&Whh[(size_t)(k0 + wk) * 2048 + 1024 + j * 64 + wn4];
      float4 w4 = *(const float4*)&Wc[(size_t)(k0 + wk) * 1024 + j * 64 + wn4];
      float4 w5 = *(const float4*)&Whc[(size_t)(k0 + wk) * 1024 + j * 64 + wn4];
      sW[0][wk][wn4] = w0.x; sW[0][wk][wn4+1] = w0.y; sW[0][wk][wn4+2] = w0.z; sW[0][wk][wn4+3] = w0.w;
      sW[1][wk][wn4] = w1.x; sW[1][wk][wn4+1] = w1.y; sW[1][wk][wn4+2] = w1.z; sW[1][wk][wn4+3] = w1.w;
      sW[2][wk][wn4] = w2.x; sW[2][wk][wn4+1] = w2.y; sW[2][wk][wn4+2] = w2.z; sW[2][wk][wn4+3] = w2.w;
      sW[3][wk][wn4] = w3.x; sW[3][wk][wn4+1] = w3.y; sW[3][wk][wn4+2] = w3.z; sW[3][wk][wn4+3] = w3.w;
      sW[4][wk][wn4] = w4.x; sW[4][wk][wn4+1] = w4.y; sW[4][wk][wn4+2] = w4.z; sW[4][wk][wn4+3] = w4.w;
      sW[5][wk][wn4] = w5.x; sW[5][wk][wn4+1] = w5.y; sW[5][wk][wn4+2] = w5.z; sW[5][wk][wn4+3] = w5.w;
    }
    __syncthreads();
    for (int kk = 0; kk < 16; ++kk) {
      float aI[4], aH[4];
      #pragma unroll
      for (int im = 0; im < 4; ++im) { aI[im] = sIn[ty * 4 + im][kk]; aH[im] = sHx[ty * 4 + im][kk]; }
      #pragma unroll
      for (int jn = 0; jn < 4; ++jn) {
        float w0 = sW[0][kk][tx * 4 + jn], w1 = sW[1][kk][tx * 4 + jn], w2 = sW[2][kk][tx * 4 + jn];
        float w3 = sW[3][kk][tx * 4 + jn], w4 = sW[4][kk][tx * 4 + jn], w5 = sW[5][kk][tx * 4 + jn];
        #pragma unroll
        for (int im = 0; im < 4; ++im) {
          accZ[im][jn] += aI[im] * w0 + aH[im] * w2;
          accR[im][jn] += aI[im] * w1 + aH[im] * w3;
          accC[im][jn] += aI[im] * w4;
          accH[im][jn] += aH[im] * w5;
        }
      }
    }
  }
  #pragma unroll
  for (int jn = 0; jn < 4; ++jn) {
    int n = j * 64 + tx * 4 + jn;
    float bz  = bih[n] + bhh[n];
    float br  = bih[1024 + n] + bhh[1024 + n];
    float bcv = bc[n], bhcv = bhc[n];
    #pragma unroll
    for (int im = 0; im < 4; ++im) {
      int m = i * 64 + ty * 4 + im;
      float z  = sigmf(accZ[im][jn] + bz);
      float rr = sigmf(accR[im][jn] + br);
      float cd = tanhf(accC[im][jn] + bcv + rr * (accH[im][jn] + bhcv));
      float h  = Hx[(size_t)m * 1024 + n];
      out[(size_t)m * 1024 + n] = (1.0f - z) * h + z * cd;
    }
  }
}

extern "C" void kernel_launch(void* const* d_in, const int* in_sizes, int n_in,
                              void* d_out, int out_size, void* d_ws, size_t ws_size,
                              hipStream_t stream) {
  const float* In  = (const float*)d_in[0];
  const float* Hx  = (const float*)d_in[1];
  const float* Wih = (const float*)d_in[2];
  const float* bih = (const float*)d_in[3];
  const float* Whh = (const float*)d_in[4];
  const float* bhh = (const float*)d_in[5];
  const float* Wc  = (const float*)d_in[6];
  const float* bc  = (const float*)d_in[7];
  const float* Whc = (const float*)d_in[8];
  const float* bhc = (const float*)d_in[9];
  float* out = (float*)d_out;

  const size_t WS_NEED = 46137344ull;
  if (ws_size >= WS_NEED) {
    unsigned short* ws    = (unsigned short*)d_ws;
    unsigned short* wsIn  = ws;
    unsigned short* wsHx  = ws + 8388608;
    unsigned short* wsWih = ws + 16777216;
    unsigned short* wsWhh = ws + 18874368;
    unsigned short* wsWc  = ws + 20971520;
    unsigned short* wsWhc = ws + 22020096;
    cvt_all<<<11264, 256, 0, stream>>>(In, Hx, Wih, Whh, Wc, Whc,
                                       wsIn, wsHx, wsWih, wsWhh, wsWc, wsWhc);
    gru_gemm<<<1024, 256, 0, stream>>>(wsIn, wsHx, wsWih, wsWhh, wsWc, wsWhc,
                                       Hx, bih, bhh, bc, bhc, out);
  } else {
    gru_fallback<<<2048, 256, 0, stream>>>(In, Hx, Wih, bih, Whh, bhh, Wc, bc, Whc, bhc, out);
  }
}